// Round 5
// baseline (392.167 us; speedup 1.0000x reference)
//
#include <hip/hip_runtime.h>
#include <hip/hip_bf16.h>

// Problem: B=32, L=1024, F=1024, H=1024, D=1024 — inputs fp32, OUTPUT fp32.
//   h1 = feat@W1 + b1; h2 = hidden@W2 + b2; att = tanh(h1 + h2[:,None,:])
//   score = att@Wp (+bp dropped: softmax shift-invariant; bp==0 anyway)
//   w = softmax_L(score); out[b][f] = sum_l w[b][l] * feat[b][l][f]
//
// ws footprint: 4.125 MB (w1t 2M + score_p 1M + h2p 1M + wts 128K).
// R3 lesson: keep ws small — 69.7 MB overflowed and corrupted pristine inputs.

typedef __attribute__((ext_vector_type(8))) __bf16 bf16x8;
typedef __attribute__((ext_vector_type(4))) float f32x4;

#define BM 128
#define BN 128
#define BK 32

static __device__ __forceinline__ ushort f2bf(float x) {  // RNE fp32->bf16
  unsigned u = __float_as_uint(x);
  return (ushort)((u + 0x7fffu + ((u >> 16) & 1u)) >> 16);
}

// async global->LDS DMA, 16 B per lane; LDS dest = wave-uniform base + lane*16
typedef __attribute__((address_space(1))) void gbl_t;
typedef __attribute__((address_space(3))) void lds_t;
static __device__ __forceinline__ void gl_lds16(const void* g, void* l) {
  __builtin_amdgcn_global_load_lds((gbl_t*)g, (lds_t*)l, 16, 0, 0);
}

static __device__ __forceinline__ bf16x8 cvt8(float4 lo, float4 hi) {
  __hip_bfloat162 c0 = __float22bfloat162_rn({lo.x, lo.y});
  __hip_bfloat162 c1 = __float22bfloat162_rn({lo.z, lo.w});
  __hip_bfloat162 c2 = __float22bfloat162_rn({hi.x, hi.y});
  __hip_bfloat162 c3 = __float22bfloat162_rn({hi.z, hi.w});
  union { int4 i; bf16x8 v; } u;
  u.i.x = *(int*)&c0; u.i.y = *(int*)&c1; u.i.z = *(int*)&c2; u.i.w = *(int*)&c3;
  return u.v;
}

// ---------------- W1 fp32 [F][D] -> W1T bf16 [D][F] ----------------
__global__ __launch_bounds__(256) void transpose_w1_kernel(
    const float* __restrict__ W1, ushort* __restrict__ W1T) {
  __shared__ float t[64][65];
  const int tr = blockIdx.y, tc = blockIdx.x, tid = threadIdx.x;
  const int r = tid >> 4;          // 0..15
  const int c4 = (tid & 15) * 4;   // 0..60
#pragma unroll
  for (int p = 0; p < 4; ++p) {
    const int rr = p * 16 + r;
    float4 v = *(const float4*)(W1 + (size_t)(tr * 64 + rr) * 1024 + tc * 64 + c4);
    t[rr][c4] = v.x; t[rr][c4 + 1] = v.y; t[rr][c4 + 2] = v.z; t[rr][c4 + 3] = v.w;
  }
  __syncthreads();
  const int cc = tid >> 3;         // 0..31
  const int r8 = (tid & 7) * 8;    // 0..56
#pragma unroll
  for (int p = 0; p < 2; ++p) {
    const int c = p * 32 + cc;
    ushort tmp[8];
#pragma unroll
    for (int j = 0; j < 8; ++j) tmp[j] = f2bf(t[r8 + j][c]);
    *(int4*)(W1T + (size_t)(tc * 64 + c) * 1024 + tr * 64 + r8) = *(int4*)tmp;
  }
}

// ---------------- zero fp32 buffer ----------------
__global__ void zero_kernel(float* __restrict__ p) {
  p[(size_t)blockIdx.x * 256 + threadIdx.x] = 0.f;
}

// ---- h2p[z][b][d] = hidden[b][128z:128z+128] @ W2[...,d] (+b2 at z==0) ----
__global__ __launch_bounds__(256) void h2_kernel(
    const float* __restrict__ hidden, const float* __restrict__ W2,
    const float* __restrict__ b2, float* __restrict__ h2p) {
  const int d = blockIdx.x * 256 + threadIdx.x;
  const int b = blockIdx.y;
  const int z = blockIdx.z;
  const int k0 = z * 128;
  __shared__ float h[128];
  if (threadIdx.x < 128) h[threadIdx.x] = hidden[b * 1024 + k0 + threadIdx.x];
  __syncthreads();
  float acc = (z == 0) ? b2[d] : 0.f;
#pragma unroll 8
  for (int k = 0; k < 128; ++k)
    acc += h[k] * W2[(size_t)(k0 + k) * 1024 + d];
  h2p[z * 32768 + b * 1024 + d] = acc;
}

// ------- fused GEMM + tanh + dot(Wp) -> score_p[by][row] (no atomics) -------
// Staging via global_load_lds w/ XOR chunk swizzle (conflict-free frag reads).
__global__ __launch_bounds__(256) void gemm_score_kernel(
    const float* __restrict__ feat,    // fp32 [32768][1024]
    const ushort* __restrict__ w1t,    // bf16 [1024][1024] = W1^T [d][f]
    const float* __restrict__ b1,      // [1024]
    const float* __restrict__ h2p,     // [8][32][1024]
    const float* __restrict__ wp,      // [1024]
    float* __restrict__ score_p) {     // [8][32768]
  __shared__ float ldsA[BM * BK];      // 16 KB fp32, chunk-swizzled
  __shared__ ushort ldsB[BN * BK];     // 8 KB bf16, chunk-swizzled
  __shared__ float sred[2][64];        // wn-pair combine
  const int tid = threadIdx.x;
  const int row0 = blockIdx.x * BM;
  const int col0 = blockIdx.y * BN;
  const int b = row0 >> 10;  // 128-row tile never crosses a batch boundary

  const int wave = tid >> 6, lane = tid & 63;
  const int wm = wave & 1, wn = wave >> 1;
  const int lrow = lane & 15;   // m (A) / n (B) / col (C)
  const int quad = lane >> 4;   // k-group (A,B) / row-group (C)

  // A: 1024 16B-chunks (row=slot>>3, kc=slot&7), 4 DMA issues/wave.
  // LDS slot (r,kc) holds global chunk (r, kc^(r&7)).
  int a_go[4], a_ls[4];
#pragma unroll
  for (int it = 0; it < 4; ++it) {
    const int slot = wave * 256 + it * 64 + lane;
    const int r = slot >> 3, kc = slot & 7;
    a_go[it] = (row0 + r) * 1024 + (kc ^ (r & 7)) * 4;  // float offset (+k0 later)
    a_ls[it] = (wave * 256 + it * 64) * 16;             // uniform LDS byte base
  }
  // B: 512 chunks (row=slot>>2, kc=slot&3), 2 issues/wave; swz=(r>>1)&3.
  int b_go[2], b_ls[2];
#pragma unroll
  for (int it = 0; it < 2; ++it) {
    const int slot = wave * 128 + it * 64 + lane;
    const int r = slot >> 2, kc = slot & 3;
    b_go[it] = (col0 + r) * 1024 + (kc ^ ((r >> 1) & 3)) * 8;  // ushort offset
    b_ls[it] = (wave * 128 + it * 64) * 16;
  }

  f32x4 acc[4][4] = {};

  for (int k0 = 0; k0 < 1024; k0 += BK) {
#pragma unroll
    for (int it = 0; it < 4; ++it)
      gl_lds16(feat + a_go[it] + k0, (char*)ldsA + a_ls[it]);
#pragma unroll
    for (int it = 0; it < 2; ++it)
      gl_lds16(w1t + b_go[it] + k0, (char*)ldsB + b_ls[it]);
    __syncthreads();  // drains vmcnt (DMA) before LDS reads

    bf16x8 af[4], bfr[4];
#pragma unroll
    for (int i = 0; i < 4; ++i) {
      const int r = wm * 64 + i * 16 + lrow;
      const int s0 = (quad * 2) ^ (r & 7);
      const int s1 = (quad * 2 + 1) ^ (r & 7);
      float4 lo = *(const float4*)&ldsA[r * 32 + s0 * 4];
      float4 hi = *(const float4*)&ldsA[r * 32 + s1 * 4];
      af[i] = cvt8(lo, hi);
    }
#pragma unroll
    for (int j = 0; j < 4; ++j) {
      const int r = wn * 64 + j * 16 + lrow;
      const int s = quad ^ ((r >> 1) & 3);
      bfr[j] = *(const bf16x8*)&ldsB[r * 32 + s * 8];
    }
#pragma unroll
    for (int i = 0; i < 4; ++i)
#pragma unroll
      for (int j = 0; j < 4; ++j)
        acc[i][j] = __builtin_amdgcn_mfma_f32_16x16x32_bf16(
            af[i], bfr[j], acc[i][j], 0, 0, 0);
    __syncthreads();
  }

  // Epilogue: tanh(h1 + b1[d] + sum_p h2p[p][b][d]) * Wp[d]; reduce over d.
  float hbv[4], wpv[4];
#pragma unroll
  for (int j = 0; j < 4; ++j) {
    const int d = col0 + wn * 64 + j * 16 + lrow;
    float hv = b1[d];
#pragma unroll
    for (int p = 0; p < 8; ++p) hv += h2p[p * 32768 + b * 1024 + d];
    hbv[j] = hv;
    wpv[j] = wp[d];
  }
  float rsum[4][4];
#pragma unroll
  for (int i = 0; i < 4; ++i) {
#pragma unroll
    for (int r = 0; r < 4; ++r) {
      float s = 0.f;
#pragma unroll
      for (int j = 0; j < 4; ++j)
        s += tanhf(acc[i][j][r] + hbv[j]) * wpv[j];
      s += __shfl_xor(s, 8);
      s += __shfl_xor(s, 4);
      s += __shfl_xor(s, 2);
      s += __shfl_xor(s, 1);
      rsum[i][r] = s;  // valid at lrow==0
    }
  }
  if (wn == 1 && lrow == 0) {
#pragma unroll
    for (int i = 0; i < 4; ++i)
#pragma unroll
      for (int r = 0; r < 4; ++r)
        sred[wm][i * 16 + quad * 4 + r] = rsum[i][r];
  }
  __syncthreads();
  if (wn == 0 && lrow == 0) {
#pragma unroll
    for (int i = 0; i < 4; ++i)
#pragma unroll
      for (int r = 0; r < 4; ++r) {
        const int ro = wm * 64 + i * 16 + quad * 4 + r;
        score_p[(size_t)blockIdx.y * 32768 + row0 + ro] =
            rsum[i][r] + sred[wm][ro & 63];
      }
  }
}

// ---------------- softmax over L per b (sums 8 score partials) ----------------
__global__ __launch_bounds__(256) void softmax_kernel(
    const float* __restrict__ score_p, float* __restrict__ w) {
  const int b = blockIdx.x, tid = threadIdx.x;
  const int lane = tid & 63, wv = tid >> 6;
  __shared__ float sm[4], ss[4];
  float v[4];
  float mx = -1e30f;
#pragma unroll
  for (int i = 0; i < 4; ++i) {
    const int idx = b * 1024 + i * 256 + tid;
    float s = 0.f;
#pragma unroll
    for (int p = 0; p < 8; ++p) s += score_p[p * 32768 + idx];
    v[i] = s;
    mx = fmaxf(mx, s);
  }
#pragma unroll
  for (int off = 32; off; off >>= 1) mx = fmaxf(mx, __shfl_xor(mx, off));
  if (lane == 0) sm[wv] = mx;
  __syncthreads();
  mx = fmaxf(fmaxf(sm[0], sm[1]), fmaxf(sm[2], sm[3]));
  float sum = 0.f;
#pragma unroll
  for (int i = 0; i < 4; ++i) {
    v[i] = __expf(v[i] - mx);
    sum += v[i];
  }
#pragma unroll
  for (int off = 32; off; off >>= 1) sum += __shfl_xor(sum, off);
  if (lane == 0) ss[wv] = sum;
  __syncthreads();
  const float inv = 1.f / (ss[0] + ss[1] + ss[2] + ss[3]);
#pragma unroll
  for (int i = 0; i < 4; ++i) w[b * 1024 + i * 256 + tid] = v[i] * inv;
}

// -------- out[b][f] += sum_{l in 32-chunk} w[b][l]*feat[b][l][f] (fp32) --------
__global__ __launch_bounds__(256) void context_kernel(
    const float* __restrict__ w, const float* __restrict__ feat,
    float* __restrict__ out) {
  const int b = blockIdx.y;
  const int l0 = blockIdx.x * 32;
  const int f0 = threadIdx.x * 4;
  __shared__ float wl[32];
  if (threadIdx.x < 32) wl[threadIdx.x] = w[b * 1024 + l0 + threadIdx.x];
  __syncthreads();
  const float* fb = feat + (size_t)b * 1048576 + (size_t)l0 * 1024 + f0;
  float a0 = 0.f, a1 = 0.f, a2 = 0.f, a3 = 0.f;
#pragma unroll 8
  for (int l = 0; l < 32; ++l) {
    float4 v = *(const float4*)(fb + (size_t)l * 1024);
    const float wv = wl[l];
    a0 += wv * v.x;
    a1 += wv * v.y;
    a2 += wv * v.z;
    a3 += wv * v.w;
  }
  float* dst = out + b * 1024 + f0;
  atomicAdd(dst + 0, a0);
  atomicAdd(dst + 1, a1);
  atomicAdd(dst + 2, a2);
  atomicAdd(dst + 3, a3);
}

extern "C" void kernel_launch(void* const* d_in, const int* in_sizes, int n_in,
                              void* d_out, int out_size, void* d_ws, size_t ws_size,
                              hipStream_t stream) {
  const float* feat   = (const float*)d_in[0];  // [32,1024,1024]
  const float* hidden = (const float*)d_in[1];  // [32,1024]
  const float* W1     = (const float*)d_in[2];  // [1024,1024]
  const float* b1     = (const float*)d_in[3];  // [1024]
  const float* W2     = (const float*)d_in[4];  // [1024,1024]
  const float* b2     = (const float*)d_in[5];  // [1024]
  const float* Wp     = (const float*)d_in[6];  // [1024]
  // d_in[7] = bp: dropped (softmax shift-invariant; also zero)
  float* out = (float*)d_out;                   // fp32 [32,1024]

  char* ws = (char*)d_ws;
  ushort* w1t    = (ushort*)ws;                  // 2 MB bf16
  float* score_p = (float*)(ws + 2097152);       // 1 MB  [8][32768]
  float* h2p     = (float*)(ws + 3145728);       // 1 MB  [8][32768]
  float* wts     = (float*)(ws + 4194304);       // 128 KB
  // total ws use: 4.125 MB

  transpose_w1_kernel<<<dim3(16, 16), 256, 0, stream>>>(W1, w1t);
  h2_kernel<<<dim3(4, 32, 8), 256, 0, stream>>>(hidden, W2, b2, h2p);
  gemm_score_kernel<<<dim3(256, 8), 256, 0, stream>>>(feat, w1t, b1, h2p, Wp,
                                                      score_p);
  softmax_kernel<<<32, 256, 0, stream>>>(score_p, wts);
  zero_kernel<<<128, 256, 0, stream>>>(out);  // d_out poisoned 0xAA pre-launch
  context_kernel<<<dim3(32, 32), 256, 0, stream>>>(wts, feat, out);
}

// Round 6
// 373.368 us; speedup vs baseline: 1.0503x; 1.0503x over previous
//
#include <hip/hip_runtime.h>
#include <hip/hip_bf16.h>

// Problem: B=32, L=1024, F=1024, H=1024, D=1024 — inputs fp32, OUTPUT fp32.
//   h1 = feat@W1 + b1; h2 = hidden@W2 + b2; att = tanh(h1 + h2[:,None,:])
//   score = att@Wp; w = softmax_L(score); out[b][f] = sum_l w[b][l]*feat[b][l][f]
//
// R5 post-mortem: inline cvt at fragment-read regressed (VALU in MFMA path).
// R6: convert feat->bf16 ONCE (half-batch chunks, 32MB) when ws_size allows
// (36.1MB needed; R3 proved ws < 69.7MB), pure-bf16 DMA GEMM; else fall back
// to R4-style staging-cvt GEMM (verified 183us).

typedef __attribute__((ext_vector_type(8))) __bf16 bf16x8;
typedef __attribute__((ext_vector_type(4))) float f32x4;

#define BM 128
#define BN 128
#define BK 32
#define LDK 40  // fallback path LDS k-stride

static __device__ __forceinline__ ushort f2bf(float x) {  // RNE fp32->bf16
  unsigned u = __float_as_uint(x);
  return (ushort)((u + 0x7fffu + ((u >> 16) & 1u)) >> 16);
}

typedef __attribute__((address_space(1))) void gbl_t;
typedef __attribute__((address_space(3))) void lds_t;
static __device__ __forceinline__ void gl_lds16(const void* g, void* l) {
  __builtin_amdgcn_global_load_lds((gbl_t*)g, (lds_t*)l, 16, 0, 0);
}

static __device__ __forceinline__ bf16x8 cvt8(float4 lo, float4 hi) {
  __hip_bfloat162 c0 = __float22bfloat162_rn({lo.x, lo.y});
  __hip_bfloat162 c1 = __float22bfloat162_rn({lo.z, lo.w});
  __hip_bfloat162 c2 = __float22bfloat162_rn({hi.x, hi.y});
  __hip_bfloat162 c3 = __float22bfloat162_rn({hi.z, hi.w});
  union { int4 i; bf16x8 v; } u;
  u.i.x = *(int*)&c0; u.i.y = *(int*)&c1; u.i.z = *(int*)&c2; u.i.w = *(int*)&c3;
  return u.v;
}

// ---------------- feat fp32 -> bf16 (16M elems per half, 8/thread) ----------------
__global__ __launch_bounds__(256) void cvt_feat_kernel(
    const float* __restrict__ feat, ushort* __restrict__ featb) {
  const size_t i8 = ((size_t)blockIdx.x * 256 + threadIdx.x) * 8;
  float4 a = *(const float4*)(feat + i8);
  float4 b = *(const float4*)(feat + i8 + 4);
  ushort t[8];
  t[0] = f2bf(a.x); t[1] = f2bf(a.y); t[2] = f2bf(a.z); t[3] = f2bf(a.w);
  t[4] = f2bf(b.x); t[5] = f2bf(b.y); t[6] = f2bf(b.z); t[7] = f2bf(b.w);
  *(int4*)(featb + i8) = *(int4*)t;
}

// ---------------- W1 fp32 [F][D] -> W1T bf16 [D][F] ----------------
__global__ __launch_bounds__(256) void transpose_w1_kernel(
    const float* __restrict__ W1, ushort* __restrict__ W1T) {
  __shared__ float t[64][65];
  const int tr = blockIdx.y, tc = blockIdx.x, tid = threadIdx.x;
  const int r = tid >> 4;
  const int c4 = (tid & 15) * 4;
#pragma unroll
  for (int p = 0; p < 4; ++p) {
    const int rr = p * 16 + r;
    float4 v = *(const float4*)(W1 + (size_t)(tr * 64 + rr) * 1024 + tc * 64 + c4);
    t[rr][c4] = v.x; t[rr][c4 + 1] = v.y; t[rr][c4 + 2] = v.z; t[rr][c4 + 3] = v.w;
  }
  __syncthreads();
  const int cc = tid >> 3;
  const int r8 = (tid & 7) * 8;
#pragma unroll
  for (int p = 0; p < 2; ++p) {
    const int c = p * 32 + cc;
    ushort tmp[8];
#pragma unroll
    for (int j = 0; j < 8; ++j) tmp[j] = f2bf(t[r8 + j][c]);
    *(int4*)(W1T + (size_t)(tc * 64 + c) * 1024 + tr * 64 + r8) = *(int4*)tmp;
  }
}

__global__ void zero_kernel(float* __restrict__ p) {
  p[(size_t)blockIdx.x * 256 + threadIdx.x] = 0.f;
}

// ---- h2p[z][b][d] = hidden[b][128z:128z+128] @ W2[...,d] (+b2 at z==0) ----
__global__ __launch_bounds__(256) void h2_kernel(
    const float* __restrict__ hidden, const float* __restrict__ W2,
    const float* __restrict__ b2, float* __restrict__ h2p) {
  const int d = blockIdx.x * 256 + threadIdx.x;
  const int b = blockIdx.y;
  const int z = blockIdx.z;
  const int k0 = z * 128;
  __shared__ float h[128];
  if (threadIdx.x < 128) h[threadIdx.x] = hidden[b * 1024 + k0 + threadIdx.x];
  __syncthreads();
  float acc = (z == 0) ? b2[d] : 0.f;
#pragma unroll 8
  for (int k = 0; k < 128; ++k)
    acc += h[k] * W2[(size_t)(k0 + k) * 1024 + d];
  h2p[z * 32768 + b * 1024 + d] = acc;
}

// ======== shared epilogue: tanh(h1+b1+h2)*wp, 16-lane reduce, score_p ========
// acc layout: C/D col=lane&15 (d), row=quad*4+reg (l within 16-tile).
#define GEMM_EPILOGUE(ROWG)                                                    \
  float hbv[4], wpv[4];                                                        \
  _Pragma("unroll") for (int j = 0; j < 4; ++j) {                              \
    const int d = col0 + wn * 64 + j * 16 + lrow;                              \
    float hv = b1[d];                                                          \
    _Pragma("unroll") for (int p = 0; p < 8; ++p)                              \
        hv += h2p[p * 32768 + b * 1024 + d];                                   \
    hbv[j] = hv;                                                               \
    wpv[j] = wp[d];                                                            \
  }                                                                            \
  float rsum[4][4];                                                            \
  _Pragma("unroll") for (int i = 0; i < 4; ++i) {                              \
    _Pragma("unroll") for (int r = 0; r < 4; ++r) {                            \
      float s = 0.f;                                                           \
      _Pragma("unroll") for (int j = 0; j < 4; ++j)                            \
          s += tanhf(acc[i][j][r] + hbv[j]) * wpv[j];                          \
      s += __shfl_xor(s, 8);                                                   \
      s += __shfl_xor(s, 4);                                                   \
      s += __shfl_xor(s, 2);                                                   \
      s += __shfl_xor(s, 1);                                                   \
      rsum[i][r] = s;                                                          \
    }                                                                          \
  }                                                                            \
  if (wn == 1 && lrow == 0) {                                                  \
    _Pragma("unroll") for (int i = 0; i < 4; ++i)                              \
        _Pragma("unroll") for (int r = 0; r < 4; ++r)                          \
            sred[wm][i * 16 + quad * 4 + r] = rsum[i][r];                      \
  }                                                                            \
  __syncthreads();                                                             \
  if (wn == 0 && lrow == 0) {                                                  \
    _Pragma("unroll") for (int i = 0; i < 4; ++i)                              \
        _Pragma("unroll") for (int r = 0; r < 4; ++r) {                        \
          const int ro = wm * 64 + i * 16 + quad * 4 + r;                      \
          score_p[(size_t)blockIdx.y * 32768 + (ROWG) + ro] =                  \
              rsum[i][r] + sred[wm][ro & 63];                                  \
        }                                                                      \
  }

// ======== PRIMARY: pure-bf16 DMA GEMM (feat pre-converted) ========
// XOR chunk swizzle: slot (r,kc) holds global chunk kc^swz(r),
// swz(r) = (r&3)^((r>>2)&3) -> frag b128 reads are 2-way/bank (free, m136).
__global__ __launch_bounds__(256) void gemm_score_bf16_kernel(
    const ushort* __restrict__ featb,  // bf16 [16384][1024] (half batch)
    const ushort* __restrict__ w1t,    // bf16 [1024][1024]
    const float* __restrict__ b1, const float* __restrict__ h2p,
    const float* __restrict__ wp, float* __restrict__ score_p,
    int row_base) {
  __shared__ ushort ldsA[BM * BK];  // 8 KB
  __shared__ ushort ldsB[BN * BK];  // 8 KB
  __shared__ float sred[2][64];
  const int tid = threadIdx.x;
  const int row0 = blockIdx.x * BM;           // local (within half)
  const int col0 = blockIdx.y * BN;
  const int b = (row_base + row0) >> 10;

  const int wave = tid >> 6, lane = tid & 63;
  const int wm = wave & 1, wn = wave >> 1;
  const int lrow = lane & 15, quad = lane >> 4;

  int a_go[2], b_go[2], ls[2];
#pragma unroll
  for (int it = 0; it < 2; ++it) {
    const int slot = wave * 128 + it * 64 + lane;  // 0..511
    const int r = slot >> 2, kc = slot & 3;
    const int swz = (r & 3) ^ ((r >> 2) & 3);
    a_go[it] = (row0 + r) * 1024 + (kc ^ swz) * 8;  // ushort offset (+k0)
    b_go[it] = (col0 + r) * 1024 + (kc ^ swz) * 8;
    ls[it] = (wave * 128 + it * 64) * 16;  // wave-uniform LDS byte base
  }

  f32x4 acc[4][4] = {};

  for (int k0 = 0; k0 < 1024; k0 += BK) {
#pragma unroll
    for (int it = 0; it < 2; ++it)
      gl_lds16(featb + a_go[it] + k0, (char*)ldsA + ls[it]);
#pragma unroll
    for (int it = 0; it < 2; ++it)
      gl_lds16(w1t + b_go[it] + k0, (char*)ldsB + ls[it]);
    __syncthreads();

    bf16x8 af[4], bfr[4];
#pragma unroll
    for (int i = 0; i < 4; ++i) {
      const int r = wm * 64 + i * 16 + lrow;
      const int swz = (r & 3) ^ ((r >> 2) & 3);
      af[i] = *(const bf16x8*)&ldsA[r * 32 + (quad ^ swz) * 8];
    }
#pragma unroll
    for (int j = 0; j < 4; ++j) {
      const int r = wn * 64 + j * 16 + lrow;
      const int swz = (r & 3) ^ ((r >> 2) & 3);
      bfr[j] = *(const bf16x8*)&ldsB[r * 32 + (quad ^ swz) * 8];
    }
#pragma unroll
    for (int i = 0; i < 4; ++i)
#pragma unroll
      for (int j = 0; j < 4; ++j)
        acc[i][j] = __builtin_amdgcn_mfma_f32_16x16x32_bf16(
            af[i], bfr[j], acc[i][j], 0, 0, 0);
    __syncthreads();
  }

  GEMM_EPILOGUE(row_base + row0)
}

// ======== FALLBACK: R4-verified staging-cvt GEMM (fp32 feat in HBM) ========
__global__ __launch_bounds__(256) void gemm_score_cvt_kernel(
    const float* __restrict__ feat,    // fp32 [32768][1024]
    const ushort* __restrict__ w1t, const float* __restrict__ b1,
    const float* __restrict__ h2p, const float* __restrict__ wp,
    float* __restrict__ score_p) {
  __shared__ ushort ldsA[BM * LDK];
  __shared__ ushort ldsB[BN * LDK];
  __shared__ float sred[2][64];
  const int tid = threadIdx.x;
  const int row0 = blockIdx.x * BM;
  const int col0 = blockIdx.y * BN;
  const int b = row0 >> 10;

  const int wave = tid >> 6, lane = tid & 63;
  const int wm = wave & 1, wn = wave >> 1;
  const int lrow = lane & 15, quad = lane >> 4;

  const int arow = tid >> 1;
  const int akof = (tid & 1) * 16;
  const int brow = tid >> 2;
  const int bkof = (tid & 3) * 8;

  f32x4 acc[4][4] = {};

  for (int k0 = 0; k0 < 1024; k0 += BK) {
    {
      const float* ap = feat + (size_t)(row0 + arow) * 1024 + k0 + akof;
      float4 v0 = *(const float4*)(ap + 0);
      float4 v1 = *(const float4*)(ap + 4);
      float4 v2 = *(const float4*)(ap + 8);
      float4 v3 = *(const float4*)(ap + 12);
      union { bf16x8 v; int4 i; } w0, w1;
      w0.v = cvt8(v0, v1);
      w1.v = cvt8(v2, v3);
      *(int4*)&ldsA[arow * LDK + akof] = w0.i;
      *(int4*)&ldsA[arow * LDK + akof + 8] = w1.i;
    }
#pragma unroll
    for (int p = 0; p < 2; ++p) {
      const int m = p * 64 + brow;
      *(int4*)&ldsB[m * LDK + bkof] =
          *(const int4*)(w1t + (size_t)(col0 + m) * 1024 + k0 + bkof);
    }
    __syncthreads();
    bf16x8 af[4], bfr[4];
#pragma unroll
    for (int i = 0; i < 4; ++i)
      af[i] = *(const bf16x8*)&ldsA[(wm * 64 + i * 16 + lrow) * LDK + quad * 8];
#pragma unroll
    for (int j = 0; j < 4; ++j)
      bfr[j] = *(const bf16x8*)&ldsB[(wn * 64 + j * 16 + lrow) * LDK + quad * 8];
#pragma unroll
    for (int i = 0; i < 4; ++i)
#pragma unroll
      for (int j = 0; j < 4; ++j)
        acc[i][j] = __builtin_amdgcn_mfma_f32_16x16x32_bf16(
            af[i], bfr[j], acc[i][j], 0, 0, 0);
    __syncthreads();
  }

  GEMM_EPILOGUE(row0)
}

// ---------------- softmax over L per b (sums 8 score partials) ----------------
__global__ __launch_bounds__(256) void softmax_kernel(
    const float* __restrict__ score_p, float* __restrict__ w) {
  const int b = blockIdx.x, tid = threadIdx.x;
  const int lane = tid & 63, wv = tid >> 6;
  __shared__ float sm[4], ss[4];
  float v[4];
  float mx = -1e30f;
#pragma unroll
  for (int i = 0; i < 4; ++i) {
    const int idx = b * 1024 + i * 256 + tid;
    float s = 0.f;
#pragma unroll
    for (int p = 0; p < 8; ++p) s += score_p[p * 32768 + idx];
    v[i] = s;
    mx = fmaxf(mx, s);
  }
#pragma unroll
  for (int off = 32; off; off >>= 1) mx = fmaxf(mx, __shfl_xor(mx, off));
  if (lane == 0) sm[wv] = mx;
  __syncthreads();
  mx = fmaxf(fmaxf(sm[0], sm[1]), fmaxf(sm[2], sm[3]));
  float sum = 0.f;
#pragma unroll
  for (int i = 0; i < 4; ++i) {
    v[i] = __expf(v[i] - mx);
    sum += v[i];
  }
#pragma unroll
  for (int off = 32; off; off >>= 1) sum += __shfl_xor(sum, off);
  if (lane == 0) ss[wv] = sum;
  __syncthreads();
  const float inv = 1.f / (ss[0] + ss[1] + ss[2] + ss[3]);
#pragma unroll
  for (int i = 0; i < 4; ++i) w[b * 1024 + i * 256 + tid] = v[i] * inv;
}

// -------- out[b][f] += sum_{l in 32-chunk} w[b][l]*feat[b][l][f] (fp32) --------
__global__ __launch_bounds__(256) void context_kernel(
    const float* __restrict__ w, const float* __restrict__ feat,
    float* __restrict__ out) {
  const int b = blockIdx.y;
  const int l0 = blockIdx.x * 32;
  const int f0 = threadIdx.x * 4;
  __shared__ float wl[32];
  if (threadIdx.x < 32) wl[threadIdx.x] = w[b * 1024 + l0 + threadIdx.x];
  __syncthreads();
  const float* fb = feat + (size_t)b * 1048576 + (size_t)l0 * 1024 + f0;
  float a0 = 0.f, a1 = 0.f, a2 = 0.f, a3 = 0.f;
#pragma unroll 8
  for (int l = 0; l < 32; ++l) {
    float4 v = *(const float4*)(fb + (size_t)l * 1024);
    const float wv = wl[l];
    a0 += wv * v.x;
    a1 += wv * v.y;
    a2 += wv * v.z;
    a3 += wv * v.w;
  }
  float* dst = out + b * 1024 + f0;
  atomicAdd(dst + 0, a0);
  atomicAdd(dst + 1, a1);
  atomicAdd(dst + 2, a2);
  atomicAdd(dst + 3, a3);
}

extern "C" void kernel_launch(void* const* d_in, const int* in_sizes, int n_in,
                              void* d_out, int out_size, void* d_ws, size_t ws_size,
                              hipStream_t stream) {
  const float* feat   = (const float*)d_in[0];
  const float* hidden = (const float*)d_in[1];
  const float* W1     = (const float*)d_in[2];
  const float* b1     = (const float*)d_in[3];
  const float* W2     = (const float*)d_in[4];
  const float* b2     = (const float*)d_in[5];
  const float* Wp     = (const float*)d_in[6];
  float* out = (float*)d_out;

  char* ws = (char*)d_ws;
  ushort* w1t    = (ushort*)ws;                  // 2 MB
  float* score_p = (float*)(ws + 2097152);       // 1 MB [8][32768]
  float* h2p     = (float*)(ws + 3145728);       // 1 MB [8][32768]
  float* wts     = (float*)(ws + 4194304);       // 128 KB
  ushort* featb  = (ushort*)(ws + 4325376);      // 32 MB (primary path only)
  const bool big_ws = ws_size >= (size_t)(4325376 + 33554432);

  transpose_w1_kernel<<<dim3(16, 16), 256, 0, stream>>>(W1, w1t);
  h2_kernel<<<dim3(4, 32, 8), 256, 0, stream>>>(hidden, W2, b2, h2p);

  if (big_ws) {
    for (int h = 0; h < 2; ++h) {
      cvt_feat_kernel<<<8192, 256, 0, stream>>>(feat + (size_t)h * 16777216,
                                                featb);
      gemm_score_bf16_kernel<<<dim3(128, 8), 256, 0, stream>>>(
          featb, w1t, b1, h2p, Wp, score_p, h * 16384);
    }
  } else {
    gemm_score_cvt_kernel<<<dim3(256, 8), 256, 0, stream>>>(feat, w1t, b1, h2p,
                                                            Wp, score_p);
  }

  softmax_kernel<<<32, 256, 0, stream>>>(score_p, wts);
  zero_kernel<<<128, 256, 0, stream>>>(out);
  context_kernel<<<dim3(32, 32), 256, 0, stream>>>(wts, feat, out);
}

// Round 7
// 346.989 us; speedup vs baseline: 1.1302x; 1.0760x over previous
//
#include <hip/hip_runtime.h>
#include <hip/hip_bf16.h>

// Problem: B=32, L=1024, F=1024, H=1024, D=1024 — inputs fp32, OUTPUT fp32.
//   h1 = feat@W1 + b1; h2 = hidden@W2 + b2; att = tanh(h1 + h2[:,None,:])
//   score = att@Wp; w = softmax_L(score); out[b][f] = sum_l w[b][l]*feat[b][l][f]
//
// R6 post-mortem: ws_size is 512MB (fill evidence); all kernels <76us.
// R7: fast-tanh epilogue (64 tanhf/thread was ~ entire MFMA loop cost),
//     BK=64 K-loop (half the barrier drains), context 64-l chunks.

typedef __attribute__((ext_vector_type(8))) __bf16 bf16x8;
typedef __attribute__((ext_vector_type(4))) float f32x4;

#define BM 128
#define BN 128
#define LDK 40  // fallback path LDS k-stride

static __device__ __forceinline__ ushort f2bf(float x) {  // RNE fp32->bf16
  unsigned u = __float_as_uint(x);
  return (ushort)((u + 0x7fffu + ((u >> 16) & 1u)) >> 16);
}

typedef __attribute__((address_space(1))) void gbl_t;
typedef __attribute__((address_space(3))) void lds_t;
static __device__ __forceinline__ void gl_lds16(const void* g, void* l) {
  __builtin_amdgcn_global_load_lds((gbl_t*)g, (lds_t*)l, 16, 0, 0);
}

static __device__ __forceinline__ bf16x8 cvt8(float4 lo, float4 hi) {
  __hip_bfloat162 c0 = __float22bfloat162_rn({lo.x, lo.y});
  __hip_bfloat162 c1 = __float22bfloat162_rn({lo.z, lo.w});
  __hip_bfloat162 c2 = __float22bfloat162_rn({hi.x, hi.y});
  __hip_bfloat162 c3 = __float22bfloat162_rn({hi.z, hi.w});
  union { int4 i; bf16x8 v; } u;
  u.i.x = *(int*)&c0; u.i.y = *(int*)&c1; u.i.z = *(int*)&c2; u.i.w = *(int*)&c3;
  return u.v;
}

// fast tanh: 1 - 2/(e^{2x}+1). exp(inf)->inf gives 1; exp(-inf)->0 gives -1.
static __device__ __forceinline__ float tanh_fast(float x) {
  float e = __expf(2.f * x);
  return 1.f - 2.f / (e + 1.f);
}

// ---------------- feat fp32 -> bf16 (16M elems per half, 8/thread) ----------------
__global__ __launch_bounds__(256) void cvt_feat_kernel(
    const float* __restrict__ feat, ushort* __restrict__ featb) {
  const size_t i8 = ((size_t)blockIdx.x * 256 + threadIdx.x) * 8;
  float4 a = *(const float4*)(feat + i8);
  float4 b = *(const float4*)(feat + i8 + 4);
  union { bf16x8 v; int4 i; } u;
  u.v = cvt8(a, b);
  *(int4*)(featb + i8) = u.i;
}

// ---------------- W1 fp32 [F][D] -> W1T bf16 [D][F] ----------------
__global__ __launch_bounds__(256) void transpose_w1_kernel(
    const float* __restrict__ W1, ushort* __restrict__ W1T) {
  __shared__ float t[64][65];
  const int tr = blockIdx.y, tc = blockIdx.x, tid = threadIdx.x;
  const int r = tid >> 4;
  const int c4 = (tid & 15) * 4;
#pragma unroll
  for (int p = 0; p < 4; ++p) {
    const int rr = p * 16 + r;
    float4 v = *(const float4*)(W1 + (size_t)(tr * 64 + rr) * 1024 + tc * 64 + c4);
    t[rr][c4] = v.x; t[rr][c4 + 1] = v.y; t[rr][c4 + 2] = v.z; t[rr][c4 + 3] = v.w;
  }
  __syncthreads();
  const int cc = tid >> 3;
  const int r8 = (tid & 7) * 8;
#pragma unroll
  for (int p = 0; p < 2; ++p) {
    const int c = p * 32 + cc;
    ushort tmp[8];
#pragma unroll
    for (int j = 0; j < 8; ++j) tmp[j] = f2bf(t[r8 + j][c]);
    *(int4*)(W1T + (size_t)(tc * 64 + c) * 1024 + tr * 64 + r8) = *(int4*)tmp;
  }
}

__global__ void zero_kernel(float* __restrict__ p) {
  p[(size_t)blockIdx.x * 256 + threadIdx.x] = 0.f;
}

// ---- h2p[z][b][d] = hidden[b][128z:128z+128] @ W2[...,d] (+b2 at z==0) ----
__global__ __launch_bounds__(256) void h2_kernel(
    const float* __restrict__ hidden, const float* __restrict__ W2,
    const float* __restrict__ b2, float* __restrict__ h2p) {
  const int d = blockIdx.x * 256 + threadIdx.x;
  const int b = blockIdx.y;
  const int z = blockIdx.z;
  const int k0 = z * 128;
  __shared__ float h[128];
  if (threadIdx.x < 128) h[threadIdx.x] = hidden[b * 1024 + k0 + threadIdx.x];
  __syncthreads();
  float acc = (z == 0) ? b2[d] : 0.f;
#pragma unroll 8
  for (int k = 0; k < 128; ++k)
    acc += h[k] * W2[(size_t)(k0 + k) * 1024 + d];
  h2p[z * 32768 + b * 1024 + d] = acc;
}

// ======== shared epilogue: fast-tanh(h1+b1+h2)*wp, 16-lane reduce, score_p ========
#define GEMM_EPILOGUE(ROWG)                                                    \
  float hbv[4], wpv[4];                                                        \
  _Pragma("unroll") for (int j = 0; j < 4; ++j) {                              \
    const int d = col0 + wn * 64 + j * 16 + lrow;                              \
    float hv = b1[d];                                                          \
    _Pragma("unroll") for (int p = 0; p < 8; ++p)                              \
        hv += h2p[p * 32768 + b * 1024 + d];                                   \
    hbv[j] = hv;                                                               \
    wpv[j] = wp[d];                                                            \
  }                                                                            \
  float rsum[4][4];                                                            \
  _Pragma("unroll") for (int i = 0; i < 4; ++i) {                              \
    _Pragma("unroll") for (int r = 0; r < 4; ++r) {                            \
      float s = 0.f;                                                           \
      _Pragma("unroll") for (int j = 0; j < 4; ++j)                            \
          s += tanh_fast(acc[i][j][r] + hbv[j]) * wpv[j];                      \
      s += __shfl_xor(s, 8);                                                   \
      s += __shfl_xor(s, 4);                                                   \
      s += __shfl_xor(s, 2);                                                   \
      s += __shfl_xor(s, 1);                                                   \
      rsum[i][r] = s;                                                          \
    }                                                                          \
  }                                                                            \
  if (wn == 1 && lrow == 0) {                                                  \
    _Pragma("unroll") for (int i = 0; i < 4; ++i)                              \
        _Pragma("unroll") for (int r = 0; r < 4; ++r)                          \
            sred[wm][i * 16 + quad * 4 + r] = rsum[i][r];                      \
  }                                                                            \
  __syncthreads();                                                             \
  if (wn == 0 && lrow == 0) {                                                  \
    _Pragma("unroll") for (int i = 0; i < 4; ++i)                              \
        _Pragma("unroll") for (int r = 0; r < 4; ++r) {                        \
          const int ro = wm * 64 + i * 16 + quad * 4 + r;                      \
          score_p[(size_t)blockIdx.y * 32768 + (ROWG) + ro] =                  \
              rsum[i][r] + sred[wm][ro & 63];                                  \
        }                                                                      \
  }

// ======== PRIMARY: pure-bf16 DMA GEMM, BK=64 (half the barrier drains) ========
// 16B-chunk XOR swizzle: LDS slot (r,c) holds global chunk (r, c^(r&7)),
// c in 0..7 (64 k = 8 chunks/row). Frag read chunk = (s*4+quad)^(r&7):
// across 16 lrow rows each bank pair is hit 2x -> 2-way = free (m136).
__global__ __launch_bounds__(256) void gemm_score_bf16_kernel(
    const ushort* __restrict__ featb,  // bf16 [16384][1024] (half batch)
    const ushort* __restrict__ w1t,    // bf16 [1024][1024]
    const float* __restrict__ b1, const float* __restrict__ h2p,
    const float* __restrict__ wp, float* __restrict__ score_p,
    int row_base) {
  __shared__ ushort ldsA[BM * 64];  // 16 KB
  __shared__ ushort ldsB[BN * 64];  // 16 KB
  __shared__ float sred[2][64];
  const int tid = threadIdx.x;
  const int row0 = blockIdx.x * BM;  // local (within half)
  const int col0 = blockIdx.y * BN;
  const int b = (row_base + row0) >> 10;

  const int wave = tid >> 6, lane = tid & 63;
  const int wm = wave & 1, wn = wave >> 1;
  const int lrow = lane & 15, quad = lane >> 4;

  // 1024 chunks each for A and B; 4 DMA issues/thread each.
  int a_go[4], b_go[4], ls[4];
#pragma unroll
  for (int it = 0; it < 4; ++it) {
    const int slot = wave * 256 + it * 64 + lane;  // 0..1023
    const int r = slot >> 3, c = slot & 7;
    const int gc = c ^ (r & 7);
    a_go[it] = (row0 + r) * 1024 + gc * 8;  // ushort offset (+k0 later)
    b_go[it] = (col0 + r) * 1024 + gc * 8;
    ls[it] = (wave * 256 + it * 64) * 16;  // wave-uniform LDS byte base
  }

  f32x4 acc[4][4] = {};

  for (int k0 = 0; k0 < 1024; k0 += 64) {
#pragma unroll
    for (int it = 0; it < 4; ++it)
      gl_lds16(featb + a_go[it] + k0, (char*)ldsA + ls[it]);
#pragma unroll
    for (int it = 0; it < 4; ++it)
      gl_lds16(w1t + b_go[it] + k0, (char*)ldsB + ls[it]);
    __syncthreads();

#pragma unroll
    for (int s = 0; s < 2; ++s) {
      bf16x8 af[4], bfr[4];
#pragma unroll
      for (int i = 0; i < 4; ++i) {
        const int r = wm * 64 + i * 16 + lrow;
        af[i] = *(const bf16x8*)&ldsA[r * 64 + (((s * 4 + quad) ^ (r & 7)) * 8)];
      }
#pragma unroll
      for (int j = 0; j < 4; ++j) {
        const int r = wn * 64 + j * 16 + lrow;
        bfr[j] = *(const bf16x8*)&ldsB[r * 64 + (((s * 4 + quad) ^ (r & 7)) * 8)];
      }
#pragma unroll
      for (int i = 0; i < 4; ++i)
#pragma unroll
        for (int j = 0; j < 4; ++j)
          acc[i][j] = __builtin_amdgcn_mfma_f32_16x16x32_bf16(
              af[i], bfr[j], acc[i][j], 0, 0, 0);
    }
    __syncthreads();
  }

  GEMM_EPILOGUE(row_base + row0)
}

// ======== FALLBACK (small ws): R4-verified staging-cvt GEMM ========
__global__ __launch_bounds__(256) void gemm_score_cvt_kernel(
    const float* __restrict__ feat, const ushort* __restrict__ w1t,
    const float* __restrict__ b1, const float* __restrict__ h2p,
    const float* __restrict__ wp, float* __restrict__ score_p) {
  __shared__ ushort ldsA[BM * LDK];
  __shared__ ushort ldsB[BN * LDK];
  __shared__ float sred[2][64];
  const int tid = threadIdx.x;
  const int row0 = blockIdx.x * BM;
  const int col0 = blockIdx.y * BN;
  const int b = row0 >> 10;

  const int wave = tid >> 6, lane = tid & 63;
  const int wm = wave & 1, wn = wave >> 1;
  const int lrow = lane & 15, quad = lane >> 4;

  const int arow = tid >> 1;
  const int akof = (tid & 1) * 16;
  const int brow = tid >> 2;
  const int bkof = (tid & 3) * 8;

  f32x4 acc[4][4] = {};

  for (int k0 = 0; k0 < 1024; k0 += 32) {
    {
      const float* ap = feat + (size_t)(row0 + arow) * 1024 + k0 + akof;
      float4 v0 = *(const float4*)(ap + 0);
      float4 v1 = *(const float4*)(ap + 4);
      float4 v2 = *(const float4*)(ap + 8);
      float4 v3 = *(const float4*)(ap + 12);
      union { bf16x8 v; int4 i; } w0, w1;
      w0.v = cvt8(v0, v1);
      w1.v = cvt8(v2, v3);
      *(int4*)&ldsA[arow * LDK + akof] = w0.i;
      *(int4*)&ldsA[arow * LDK + akof + 8] = w1.i;
    }
#pragma unroll
    for (int p = 0; p < 2; ++p) {
      const int m = p * 64 + brow;
      *(int4*)&ldsB[m * LDK + bkof] =
          *(const int4*)(w1t + (size_t)(col0 + m) * 1024 + k0 + bkof);
    }
    __syncthreads();
    bf16x8 af[4], bfr[4];
#pragma unroll
    for (int i = 0; i < 4; ++i)
      af[i] = *(const bf16x8*)&ldsA[(wm * 64 + i * 16 + lrow) * LDK + quad * 8];
#pragma unroll
    for (int j = 0; j < 4; ++j)
      bfr[j] = *(const bf16x8*)&ldsB[(wn * 64 + j * 16 + lrow) * LDK + quad * 8];
#pragma unroll
    for (int i = 0; i < 4; ++i)
#pragma unroll
      for (int j = 0; j < 4; ++j)
        acc[i][j] = __builtin_amdgcn_mfma_f32_16x16x32_bf16(
            af[i], bfr[j], acc[i][j], 0, 0, 0);
    __syncthreads();
  }

  GEMM_EPILOGUE(row0)
}

// ---------------- softmax over L per b (sums 8 score partials) ----------------
__global__ __launch_bounds__(256) void softmax_kernel(
    const float* __restrict__ score_p, float* __restrict__ w) {
  const int b = blockIdx.x, tid = threadIdx.x;
  const int lane = tid & 63, wv = tid >> 6;
  __shared__ float sm[4], ss[4];
  float v[4];
  float mx = -1e30f;
#pragma unroll
  for (int i = 0; i < 4; ++i) {
    const int idx = b * 1024 + i * 256 + tid;
    float s = 0.f;
#pragma unroll
    for (int p = 0; p < 8; ++p) s += score_p[p * 32768 + idx];
    v[i] = s;
    mx = fmaxf(mx, s);
  }
#pragma unroll
  for (int off = 32; off; off >>= 1) mx = fmaxf(mx, __shfl_xor(mx, off));
  if (lane == 0) sm[wv] = mx;
  __syncthreads();
  mx = fmaxf(fmaxf(sm[0], sm[1]), fmaxf(sm[2], sm[3]));
  float sum = 0.f;
#pragma unroll
  for (int i = 0; i < 4; ++i) {
    v[i] = __expf(v[i] - mx);
    sum += v[i];
  }
#pragma unroll
  for (int off = 32; off; off >>= 1) sum += __shfl_xor(sum, off);
  if (lane == 0) ss[wv] = sum;
  __syncthreads();
  const float inv = 1.f / (ss[0] + ss[1] + ss[2] + ss[3]);
#pragma unroll
  for (int i = 0; i < 4; ++i) w[b * 1024 + i * 256 + tid] = v[i] * inv;
}

// -------- out[b][f] += sum_{l in 64-chunk} w[b][l]*feat[b][l][f] (fp32) --------
__global__ __launch_bounds__(256) void context_kernel(
    const float* __restrict__ w, const float* __restrict__ feat,
    float* __restrict__ out) {
  const int b = blockIdx.y;
  const int l0 = blockIdx.x * 64;
  const int f0 = threadIdx.x * 4;
  __shared__ float wl[64];
  if (threadIdx.x < 64) wl[threadIdx.x] = w[b * 1024 + l0 + threadIdx.x];
  __syncthreads();
  const float* fb = feat + (size_t)b * 1048576 + (size_t)l0 * 1024 + f0;
  float a0 = 0.f, a1 = 0.f, a2 = 0.f, a3 = 0.f;
#pragma unroll 8
  for (int l = 0; l < 64; ++l) {
    float4 v = *(const float4*)(fb + (size_t)l * 1024);
    const float wv = wl[l];
    a0 += wv * v.x;
    a1 += wv * v.y;
    a2 += wv * v.z;
    a3 += wv * v.w;
  }
  float* dst = out + b * 1024 + f0;
  atomicAdd(dst + 0, a0);
  atomicAdd(dst + 1, a1);
  atomicAdd(dst + 2, a2);
  atomicAdd(dst + 3, a3);
}

extern "C" void kernel_launch(void* const* d_in, const int* in_sizes, int n_in,
                              void* d_out, int out_size, void* d_ws, size_t ws_size,
                              hipStream_t stream) {
  const float* feat   = (const float*)d_in[0];
  const float* hidden = (const float*)d_in[1];
  const float* W1     = (const float*)d_in[2];
  const float* b1     = (const float*)d_in[3];
  const float* W2     = (const float*)d_in[4];
  const float* b2     = (const float*)d_in[5];
  const float* Wp     = (const float*)d_in[6];
  float* out = (float*)d_out;

  char* ws = (char*)d_ws;
  ushort* w1t    = (ushort*)ws;                  // 2 MB
  float* score_p = (float*)(ws + 2097152);       // 1 MB [8][32768]
  float* h2p     = (float*)(ws + 3145728);       // 1 MB [8][32768]
  float* wts     = (float*)(ws + 4194304);       // 128 KB
  ushort* featb  = (ushort*)(ws + 4325376);      // 32 MB (primary path only)
  const bool big_ws = ws_size >= (size_t)(4325376 + 33554432);

  transpose_w1_kernel<<<dim3(16, 16), 256, 0, stream>>>(W1, w1t);
  h2_kernel<<<dim3(4, 32, 8), 256, 0, stream>>>(hidden, W2, b2, h2p);

  if (big_ws) {
    for (int h = 0; h < 2; ++h) {
      cvt_feat_kernel<<<8192, 256, 0, stream>>>(feat + (size_t)h * 16777216,
                                                featb);
      gemm_score_bf16_kernel<<<dim3(128, 8), 256, 0, stream>>>(
          featb, w1t, b1, h2p, Wp, score_p, h * 16384);
    }
  } else {
    gemm_score_cvt_kernel<<<dim3(256, 8), 256, 0, stream>>>(feat, w1t, b1, h2p,
                                                            Wp, score_p);
  }

  softmax_kernel<<<32, 256, 0, stream>>>(score_p, wts);
  zero_kernel<<<128, 256, 0, stream>>>(out);
  context_kernel<<<dim3(16, 32), 256, 0, stream>>>(wts, feat, out);
}

// Round 8
// 340.389 us; speedup vs baseline: 1.1521x; 1.0194x over previous
//
#include <hip/hip_runtime.h>
#include <hip/hip_bf16.h>

// Problem: B=32, L=1024, F=1024, H=1024, D=1024 — inputs fp32, OUTPUT fp32.
//   h1 = feat@W1 + b1; h2 = hidden@W2 + b2; att = tanh(h1 + h2[:,None,:])
//   score = att@Wp; w = softmax_L(score); out[b][f] = sum_l w[b][l]*feat[b][l][f]
//
// R7 post-mortem: ws=512MB (fill evidence), all own kernels <76us; ~100us of
// the 347 is dispatch overhead + under-modeled small kernels + fat epilogue.
// R8: 6 dispatches (prep merges cvt+transpose+h2; softmax zeroes out),
//     epilogue hb/wp hoisted to per-block LDS precompute.

typedef __attribute__((ext_vector_type(8))) __bf16 bf16x8;
typedef __attribute__((ext_vector_type(4))) float f32x4;

#define BM 128
#define BN 128
#define LDK 40  // fallback path LDS k-stride

static __device__ __forceinline__ ushort f2bf(float x) {  // RNE fp32->bf16
  unsigned u = __float_as_uint(x);
  return (ushort)((u + 0x7fffu + ((u >> 16) & 1u)) >> 16);
}

typedef __attribute__((address_space(1))) void gbl_t;
typedef __attribute__((address_space(3))) void lds_t;
static __device__ __forceinline__ void gl_lds16(const void* g, void* l) {
  __builtin_amdgcn_global_load_lds((gbl_t*)g, (lds_t*)l, 16, 0, 0);
}

static __device__ __forceinline__ bf16x8 cvt8(float4 lo, float4 hi) {
  __hip_bfloat162 c0 = __float22bfloat162_rn({lo.x, lo.y});
  __hip_bfloat162 c1 = __float22bfloat162_rn({lo.z, lo.w});
  __hip_bfloat162 c2 = __float22bfloat162_rn({hi.x, hi.y});
  __hip_bfloat162 c3 = __float22bfloat162_rn({hi.z, hi.w});
  union { int4 i; bf16x8 v; } u;
  u.i.x = *(int*)&c0; u.i.y = *(int*)&c1; u.i.z = *(int*)&c2; u.i.w = *(int*)&c3;
  return u.v;
}

// fast tanh: 1 - 2/(e^{2x}+1). exp(+inf)->inf gives 1; exp(-inf)->0 gives -1.
static __device__ __forceinline__ float tanh_fast(float x) {
  float e = __expf(2.f * x);
  return 1.f - 2.f / (e + 1.f);
}

// ---------- prep: [0,cvt_blocks) feat-half cvt | +256 W1 transpose | +1024 h2 ----------
__global__ __launch_bounds__(256) void prep_kernel(
    const float* __restrict__ feat_half, ushort* __restrict__ featb,
    const float* __restrict__ W1, ushort* __restrict__ w1t,
    const float* __restrict__ hidden, const float* __restrict__ W2,
    const float* __restrict__ b2, float* __restrict__ h2p, int cvt_blocks) {
  __shared__ float smem[64 * 65];
  const int bx = blockIdx.x, tid = threadIdx.x;
  if (bx < cvt_blocks) {
    // feat fp32 -> bf16, 8 elems/thread over 16M elems (half batch)
    const size_t i8 = ((size_t)bx * 256 + tid) * 8;
    float4 a = *(const float4*)(feat_half + i8);
    float4 c = *(const float4*)(feat_half + i8 + 4);
    union { bf16x8 v; int4 i; } u;
    u.v = cvt8(a, c);
    *(int4*)(featb + i8) = u.i;
  } else if (bx < cvt_blocks + 256) {
    // W1 [F][D] fp32 -> W1T [D][F] bf16, 64x64 tiles
    const int t = bx - cvt_blocks;
    const int tc = t & 15, tr = t >> 4;
    float (*tt)[65] = (float(*)[65])smem;
    const int r = tid >> 4, c4 = (tid & 15) * 4;
#pragma unroll
    for (int p = 0; p < 4; ++p) {
      const int rr = p * 16 + r;
      float4 v = *(const float4*)(W1 + (size_t)(tr * 64 + rr) * 1024 + tc * 64 + c4);
      tt[rr][c4] = v.x; tt[rr][c4 + 1] = v.y; tt[rr][c4 + 2] = v.z; tt[rr][c4 + 3] = v.w;
    }
    __syncthreads();
    const int cc = tid >> 3, r8 = (tid & 7) * 8;
#pragma unroll
    for (int p = 0; p < 2; ++p) {
      const int c = p * 32 + cc;
      ushort tmp[8];
#pragma unroll
      for (int j = 0; j < 8; ++j) tmp[j] = f2bf(tt[r8 + j][c]);
      *(int4*)(w1t + (size_t)(tc * 64 + c) * 1024 + tr * 64 + r8) = *(int4*)tmp;
    }
  } else {
    // h2p[z][b][d] = hidden[b][128z:+128] @ W2[...,d] (+b2 at z==0)
    const int t = bx - cvt_blocks - 256;  // 0..1023
    const int dblk = t & 3, b = (t >> 2) & 31, z = t >> 7;
    const int d = dblk * 256 + tid;
    const int k0 = z * 128;
    float* h = smem;
    if (tid < 128) h[tid] = hidden[b * 1024 + k0 + tid];
    __syncthreads();
    float acc = (z == 0) ? b2[d] : 0.f;
#pragma unroll 8
    for (int k = 0; k < 128; ++k)
      acc += h[k] * W2[(size_t)(k0 + k) * 1024 + d];
    h2p[z * 32768 + b * 1024 + d] = acc;
  }
}

// ======== shared pre-loop (hb/wp to LDS) + epilogue ========
#define GEMM_PRELOOP()                                                         \
  if (tid < 128) {                                                             \
    const int d = col0 + tid;                                                  \
    float hv = b1[d];                                                          \
    _Pragma("unroll") for (int p = 0; p < 8; ++p)                              \
        hv += h2p[p * 32768 + b * 1024 + d];                                   \
    hbl[tid] = hv;                                                             \
  } else {                                                                     \
    wpl[tid - 128] = wp[col0 + tid - 128];                                     \
  }

#define GEMM_EPILOGUE(ROWG)                                                    \
  float hbv[4], wpv[4];                                                        \
  _Pragma("unroll") for (int j = 0; j < 4; ++j) {                              \
    const int idx = wn * 64 + j * 16 + lrow;                                   \
    hbv[j] = hbl[idx];                                                         \
    wpv[j] = wpl[idx];                                                         \
  }                                                                            \
  float rsum[4][4];                                                            \
  _Pragma("unroll") for (int i = 0; i < 4; ++i) {                              \
    _Pragma("unroll") for (int r = 0; r < 4; ++r) {                            \
      float s = 0.f;                                                           \
      _Pragma("unroll") for (int j = 0; j < 4; ++j)                            \
          s += tanh_fast(acc[i][j][r] + hbv[j]) * wpv[j];                      \
      s += __shfl_xor(s, 8);                                                   \
      s += __shfl_xor(s, 4);                                                   \
      s += __shfl_xor(s, 2);                                                   \
      s += __shfl_xor(s, 1);                                                   \
      rsum[i][r] = s;                                                          \
    }                                                                          \
  }                                                                            \
  if (wn == 1 && lrow == 0) {                                                  \
    _Pragma("unroll") for (int i = 0; i < 4; ++i)                              \
        _Pragma("unroll") for (int r = 0; r < 4; ++r)                          \
            sred[wm][i * 16 + quad * 4 + r] = rsum[i][r];                      \
  }                                                                            \
  __syncthreads();                                                             \
  if (wn == 0 && lrow == 0) {                                                  \
    _Pragma("unroll") for (int i = 0; i < 4; ++i)                              \
        _Pragma("unroll") for (int r = 0; r < 4; ++r) {                        \
          const int ro = wm * 64 + i * 16 + quad * 4 + r;                      \
          score_p[(size_t)blockIdx.y * 32768 + (ROWG) + ro] =                  \
              rsum[i][r] + sred[wm][ro & 63];                                  \
        }                                                                      \
  }

// ======== PRIMARY: pure-bf16 DMA GEMM, BK=64 ========
// 16B-chunk XOR swizzle: LDS slot (r,c) holds global chunk (r, c^(r&7)).
__global__ __launch_bounds__(256) void gemm_score_bf16_kernel(
    const ushort* __restrict__ featb,  // bf16 [16384][1024] (half batch)
    const ushort* __restrict__ w1t,    // bf16 [1024][1024]
    const float* __restrict__ b1, const float* __restrict__ h2p,
    const float* __restrict__ wp, float* __restrict__ score_p,
    int row_base) {
  __shared__ ushort ldsA[BM * 64];  // 16 KB
  __shared__ ushort ldsB[BN * 64];  // 16 KB
  __shared__ float sred[2][64];
  __shared__ float hbl[128], wpl[128];
  const int tid = threadIdx.x;
  const int row0 = blockIdx.x * BM;  // local (within half)
  const int col0 = blockIdx.y * BN;
  const int b = (row_base + row0) >> 10;

  const int wave = tid >> 6, lane = tid & 63;
  const int wm = wave & 1, wn = wave >> 1;
  const int lrow = lane & 15, quad = lane >> 4;

  GEMM_PRELOOP()  // visibility covered by first K-loop barrier

  int a_go[4], b_go[4], ls[4];
#pragma unroll
  for (int it = 0; it < 4; ++it) {
    const int slot = wave * 256 + it * 64 + lane;  // 0..1023
    const int r = slot >> 3, c = slot & 7;
    const int gc = c ^ (r & 7);
    a_go[it] = (row0 + r) * 1024 + gc * 8;
    b_go[it] = (col0 + r) * 1024 + gc * 8;
    ls[it] = (wave * 256 + it * 64) * 16;
  }

  f32x4 acc[4][4] = {};

  for (int k0 = 0; k0 < 1024; k0 += 64) {
#pragma unroll
    for (int it = 0; it < 4; ++it)
      gl_lds16(featb + a_go[it] + k0, (char*)ldsA + ls[it]);
#pragma unroll
    for (int it = 0; it < 4; ++it)
      gl_lds16(w1t + b_go[it] + k0, (char*)ldsB + ls[it]);
    __syncthreads();

#pragma unroll
    for (int s = 0; s < 2; ++s) {
      bf16x8 af[4], bfr[4];
#pragma unroll
      for (int i = 0; i < 4; ++i) {
        const int r = wm * 64 + i * 16 + lrow;
        af[i] = *(const bf16x8*)&ldsA[r * 64 + (((s * 4 + quad) ^ (r & 7)) * 8)];
      }
#pragma unroll
      for (int j = 0; j < 4; ++j) {
        const int r = wn * 64 + j * 16 + lrow;
        bfr[j] = *(const bf16x8*)&ldsB[r * 64 + (((s * 4 + quad) ^ (r & 7)) * 8)];
      }
#pragma unroll
      for (int i = 0; i < 4; ++i)
#pragma unroll
        for (int j = 0; j < 4; ++j)
          acc[i][j] = __builtin_amdgcn_mfma_f32_16x16x32_bf16(
              af[i], bfr[j], acc[i][j], 0, 0, 0);
    }
    __syncthreads();
  }

  GEMM_EPILOGUE(row_base + row0)
}

// ======== FALLBACK (small ws): staging-cvt GEMM, fp32 feat direct ========
__global__ __launch_bounds__(256) void gemm_score_cvt_kernel(
    const float* __restrict__ feat, const ushort* __restrict__ w1t,
    const float* __restrict__ b1, const float* __restrict__ h2p,
    const float* __restrict__ wp, float* __restrict__ score_p) {
  __shared__ ushort ldsA[BM * LDK];
  __shared__ ushort ldsB[BN * LDK];
  __shared__ float sred[2][64];
  __shared__ float hbl[128], wpl[128];
  const int tid = threadIdx.x;
  const int row0 = blockIdx.x * BM;
  const int col0 = blockIdx.y * BN;
  const int b = row0 >> 10;

  const int wave = tid >> 6, lane = tid & 63;
  const int wm = wave & 1, wn = wave >> 1;
  const int lrow = lane & 15, quad = lane >> 4;

  GEMM_PRELOOP()

  const int arow = tid >> 1;
  const int akof = (tid & 1) * 16;
  const int brow = tid >> 2;
  const int bkof = (tid & 3) * 8;

  f32x4 acc[4][4] = {};

  for (int k0 = 0; k0 < 1024; k0 += 32) {
    {
      const float* ap = feat + (size_t)(row0 + arow) * 1024 + k0 + akof;
      float4 v0 = *(const float4*)(ap + 0);
      float4 v1 = *(const float4*)(ap + 4);
      float4 v2 = *(const float4*)(ap + 8);
      float4 v3 = *(const float4*)(ap + 12);
      union { bf16x8 v; int4 i; } w0, w1;
      w0.v = cvt8(v0, v1);
      w1.v = cvt8(v2, v3);
      *(int4*)&ldsA[arow * LDK + akof] = w0.i;
      *(int4*)&ldsA[arow * LDK + akof + 8] = w1.i;
    }
#pragma unroll
    for (int p = 0; p < 2; ++p) {
      const int m = p * 64 + brow;
      *(int4*)&ldsB[m * LDK + bkof] =
          *(const int4*)(w1t + (size_t)(col0 + m) * 1024 + k0 + bkof);
    }
    __syncthreads();
    bf16x8 af[4], bfr[4];
#pragma unroll
    for (int i = 0; i < 4; ++i)
      af[i] = *(const bf16x8*)&ldsA[(wm * 64 + i * 16 + lrow) * LDK + quad * 8];
#pragma unroll
    for (int j = 0; j < 4; ++j)
      bfr[j] = *(const bf16x8*)&ldsB[(wn * 64 + j * 16 + lrow) * LDK + quad * 8];
#pragma unroll
    for (int i = 0; i < 4; ++i)
#pragma unroll
      for (int j = 0; j < 4; ++j)
        acc[i][j] = __builtin_amdgcn_mfma_f32_16x16x32_bf16(
            af[i], bfr[j], acc[i][j], 0, 0, 0);
    __syncthreads();
  }

  GEMM_EPILOGUE(row0)
}

// -------- softmax over L per b (sums 8 partials); also zeroes out[b][:] --------
__global__ __launch_bounds__(256) void softmax_kernel(
    const float* __restrict__ score_p, float* __restrict__ w,
    float* __restrict__ out) {
  const int b = blockIdx.x, tid = threadIdx.x;
  const int lane = tid & 63, wv = tid >> 6;
  __shared__ float sm[4], ss[4];
  float v[4];
  float mx = -1e30f;
#pragma unroll
  for (int i = 0; i < 4; ++i) {
    const int idx = b * 1024 + i * 256 + tid;
    out[idx] = 0.f;  // d_out poisoned 0xAA; context atomicAdds later
    float s = 0.f;
#pragma unroll
    for (int p = 0; p < 8; ++p) s += score_p[p * 32768 + idx];
    v[i] = s;
    mx = fmaxf(mx, s);
  }
#pragma unroll
  for (int off = 32; off; off >>= 1) mx = fmaxf(mx, __shfl_xor(mx, off));
  if (lane == 0) sm[wv] = mx;
  __syncthreads();
  mx = fmaxf(fmaxf(sm[0], sm[1]), fmaxf(sm[2], sm[3]));
  float sum = 0.f;
#pragma unroll
  for (int i = 0; i < 4; ++i) {
    v[i] = __expf(v[i] - mx);
    sum += v[i];
  }
#pragma unroll
  for (int off = 32; off; off >>= 1) sum += __shfl_xor(sum, off);
  if (lane == 0) ss[wv] = sum;
  __syncthreads();
  const float inv = 1.f / (ss[0] + ss[1] + ss[2] + ss[3]);
#pragma unroll
  for (int i = 0; i < 4; ++i) w[b * 1024 + i * 256 + tid] = v[i] * inv;
}

// -------- out[b][f] += sum_{l in 64-chunk} w[b][l]*feat[b][l][f] (fp32) --------
__global__ __launch_bounds__(256) void context_kernel(
    const float* __restrict__ w, const float* __restrict__ feat,
    float* __restrict__ out) {
  const int b = blockIdx.y;
  const int l0 = blockIdx.x * 64;
  const int f0 = threadIdx.x * 4;
  __shared__ float wl[64];
  if (threadIdx.x < 64) wl[threadIdx.x] = w[b * 1024 + l0 + threadIdx.x];
  __syncthreads();
  const float* fb = feat + (size_t)b * 1048576 + (size_t)l0 * 1024 + f0;
  float a0 = 0.f, a1 = 0.f, a2 = 0.f, a3 = 0.f;
#pragma unroll 8
  for (int l = 0; l < 64; ++l) {
    float4 v = *(const float4*)(fb + (size_t)l * 1024);
    const float wv = wl[l];
    a0 += wv * v.x;
    a1 += wv * v.y;
    a2 += wv * v.z;
    a3 += wv * v.w;
  }
  float* dst = out + b * 1024 + f0;
  atomicAdd(dst + 0, a0);
  atomicAdd(dst + 1, a1);
  atomicAdd(dst + 2, a2);
  atomicAdd(dst + 3, a3);
}

extern "C" void kernel_launch(void* const* d_in, const int* in_sizes, int n_in,
                              void* d_out, int out_size, void* d_ws, size_t ws_size,
                              hipStream_t stream) {
  const float* feat   = (const float*)d_in[0];
  const float* hidden = (const float*)d_in[1];
  const float* W1     = (const float*)d_in[2];
  const float* b1     = (const float*)d_in[3];
  const float* W2     = (const float*)d_in[4];
  const float* b2     = (const float*)d_in[5];
  const float* Wp     = (const float*)d_in[6];
  float* out = (float*)d_out;

  char* ws = (char*)d_ws;
  ushort* w1t    = (ushort*)ws;                  // 2 MB
  float* score_p = (float*)(ws + 2097152);       // 1 MB [8][32768]
  float* h2p     = (float*)(ws + 3145728);       // 1 MB [8][32768]
  float* wts     = (float*)(ws + 4194304);       // 128 KB
  ushort* featb  = (ushort*)(ws + 4325376);      // 32 MB (primary path only)
  const bool big_ws = ws_size >= (size_t)(4325376 + 33554432);

  if (big_ws) {
    // prep: cvt(h0) 8192 blocks + transpose 256 + h2 1024
    prep_kernel<<<9472, 256, 0, stream>>>(feat, featb, W1, w1t, hidden, W2, b2,
                                          h2p, 8192);
    gemm_score_bf16_kernel<<<dim3(128, 8), 256, 0, stream>>>(
        featb, w1t, b1, h2p, Wp, score_p, 0);
    prep_kernel<<<8192, 256, 0, stream>>>(feat + 16777216, featb, W1, w1t,
                                          hidden, W2, b2, h2p, 8192);
    gemm_score_bf16_kernel<<<dim3(128, 8), 256, 0, stream>>>(
        featb, w1t, b1, h2p, Wp, score_p, 16384);
  } else {
    prep_kernel<<<1280, 256, 0, stream>>>(feat, featb, W1, w1t, hidden, W2, b2,
                                          h2p, 0);
    gemm_score_cvt_kernel<<<dim3(256, 8), 256, 0, stream>>>(feat, w1t, b1, h2p,
                                                            Wp, score_p);
  }

  softmax_kernel<<<32, 256, 0, stream>>>(score_p, wts, out);
  context_kernel<<<dim3(16, 32), 256, 0, stream>>>(wts, feat, out);
}